// Round 4
// baseline (133.428 us; speedup 1.0000x reference)
//
#include <hip/hip_runtime.h>
#include <hip/hip_bf16.h>
#include <math.h>

#define PI_D 3.14159265358979323846
#define NLAT 128
#define NLON 256
#define LMAX 50
#define MMAX 50
#define NPTS 2048
#define NFIELD 4   // {pred,target} x {b0,b1}
#define MGRID (NLAT * NLON)
#define BIGF __uint_as_float(0x7F000000u)   // ~1.7e38, finite

typedef float v2f __attribute__((ext_vector_type(2)));

__device__ __forceinline__ void insert3(float kf, float& k0, float& k1, float& k2) {
    float n1 = __builtin_amdgcn_fmed3f(kf, k0, k1);
    float n2 = __builtin_amdgcn_fmed3f(kf, k1, k2);
    k0 = fminf(kf, k0);
    k1 = n1;
    k2 = n2;
}

// ---------------------------------------------------------------------------
// Kernel 1 (fused): blocks 0..511  = knn+interp+DFT, one (field, lat-row) each,
//                   512 threads: 2 threads per lon (each scans 1024 candidates).
//                   blocks 512..561 = PCTW table transposed [l][k][m];
//                   block 512 also zeroes out[0].
// ---------------------------------------------------------------------------
__global__ __launch_bounds__(512) void fused_main(
    const float* __restrict__ pred, const float* __restrict__ tgt,
    float* __restrict__ pctwT, float* __restrict__ fre, float* __restrict__ out) {

    __shared__ float s_th[NPTS];     // theta          8 KB
    __shared__ float s_az[NPTS];     // az - pi        8 KB
    __shared__ float s_r[NPTS];      // radius         8 KB
    __shared__ float ctab[NLON];     // DFT twiddles   1 KB
    __shared__ float row[NLON];      // interp row     1 KB
    __shared__ float s_pair[256 * 3];// partner top-3  3 KB
    __shared__ float part[400];      // DFT partials  1.6 KB
    __shared__ double sa[LMAX], sb[LMAX], sc[LMAX];

    int bid = blockIdx.x;
    int t = threadIdx.x;

    if (bid >= 512) {
        // ---------------- PCTW role (transposed output [l][k][m]) ----------
        int m = bid - 512;           // 0..49
        if (m == 0 && t == 0) out[0] = 0.0f;  // init for contract's atomics
        if (t < LMAX) {
            int l = t;
            double av = 0.0, bv = 0.0;
            if (l >= m + 2) {
                double ll = (double)l;
                double denom = ll * ll - (double)(m * m);
                av = sqrt((4.0 * ll * ll - 1.0) / denom);
                bv = sqrt(((2.0 * ll + 1.0) * (double)(l - 1 + m) * (double)(l - 1 - m)) /
                          ((2.0 * ll - 3.0) * denom));
            }
            sa[l] = av;
            sb[l] = bv;
            sc[l] = (l >= 1) ? sqrt((2.0 * (double)l + 1.0) / (2.0 * (double)l)) : 0.0;
        }
        __syncthreads();
        if (t < NLAT) {
            int k = t;
            double theta = PI_D * (double)k / 127.0;
            double cost = cos(theta);
            double sint = sqrt(fmax(1.0 - cost * cost, 0.0));
            // Clenshaw-Curtis weight via Chebyshev recurrence (Nn=127, odd)
            double c2 = cos(2.0 * theta);
            double two_c2 = 2.0 * c2;
            double cp = 1.0, cc = c2, v = 0.0;
            for (int tt = 1; tt <= 63; ++tt) {
                v += 2.0 * cc / (double)(4 * tt * tt - 1);
                double cn = two_c2 * cc - cp;
                cp = cc;
                cc = cn;
            }
            double w = (2.0 / 127.0) * (1.0 - v);
            if (k == 0 || k == 127) w *= 0.5;

            double pmm = sqrt(1.0 / (4.0 * PI_D));
            for (int i = 1; i <= m; ++i) pmm = -pmm * sc[i] * sint;

            // write pctwT[(l*NLAT+k)*MMAX + m]
            float* o = pctwT + (size_t)k * MMAX + m;
            for (int l = 0; l < m; ++l) o[(size_t)l * NLAT * MMAX] = 0.0f;
            o[(size_t)m * NLAT * MMAX] = (float)(pmm * w);
            double plm2 = pmm, plm1 = 0.0;
            if (m + 1 < LMAX) {
                plm1 = sqrt(2.0 * (double)m + 3.0) * cost * pmm;
                o[(size_t)(m + 1) * NLAT * MMAX] = (float)(plm1 * w);
            }
            for (int l = m + 2; l < LMAX; ++l) {
                double p = sa[l] * cost * plm1 - sb[l] * plm2;
                o[(size_t)l * NLAT * MMAX] = (float)(p * w);
                plm2 = plm1;
                plm1 = p;
            }
        }
        return;
    }

    // ---------------- KNN + interp + DFT role ----------------
    int f = bid >> 7;         // 0..3: {pred b0, pred b1, tgt b0, tgt b1}
    int lat = bid & 127;      // lat row
    const float* src = ((f < 2) ? pred : tgt) + (size_t)(f & 1) * NPTS * 3;

    // inline to_spherical into LDS (same fp order as reference)
    for (int n = t; n < NPTS; n += 512) {
        float x = src[3 * n], y = src[3 * n + 1], z = src[3 * n + 2];
        float s1 = z * z;
        float s2 = s1 + y * y;
        float s3 = s2 + x * x;
        float r = sqrtf(s3);
        float rho = sqrtf(s2);
        float theta = acosf(x / r);
        float a = acosf(y / rho);
        float az = (z < 0.0f) ? (a + (2.0f * (float)PI_D - 2.0f * a)) : a;
        az -= (float)PI_D;
        s_th[n] = theta;
        s_az[n] = az;
        s_r[n] = r;
    }
    if (t < NLON) ctab[t] = (float)cos(2.0 * PI_D * (double)t / (double)NLON);
    __syncthreads();

    int j = t & 255;          // lon
    int half = t >> 8;        // which 1024-candidate half this thread scans
    float gl = (float)(((double)j - 128.0) * PI_D / 128.0);
    float gt = (float)((double)lat * PI_D / 128.0);
    v2f gt2 = {gt, gt}, gl2 = {gl, gl};

    float k0 = BIGF, k1 = BIGF, k2 = BIGF;
    const float4* th4 = (const float4*)s_th;
    const float4* az4 = (const float4*)s_az;
    int cbase = half * (NPTS / 2 / 4);   // in float4 units

#pragma unroll 2
    for (int c = 0; c < NPTS / 2 / 4; ++c) {
        float4 th = th4[cbase + c];
        float4 az = az4[cbase + c];
        int nb = half * (NPTS / 2) + 4 * c;
        {
            v2f tha = {th.x, th.y}, aza = {az.x, az.y};
            v2f dt = gt2 - tha;
            v2f dl = gl2 - aza;
            v2f d = __builtin_elementwise_fma(dt, dt, dl * dl);
            unsigned ka = (__float_as_uint(d.x) & 0xFFFFF800u) | (unsigned)(nb + 0);
            insert3(__uint_as_float(ka), k0, k1, k2);
            unsigned kb = (__float_as_uint(d.y) & 0xFFFFF800u) | (unsigned)(nb + 1);
            insert3(__uint_as_float(kb), k0, k1, k2);
        }
        {
            v2f tha = {th.z, th.w}, aza = {az.z, az.w};
            v2f dt = gt2 - tha;
            v2f dl = gl2 - aza;
            v2f d = __builtin_elementwise_fma(dt, dt, dl * dl);
            unsigned ka = (__float_as_uint(d.x) & 0xFFFFF800u) | (unsigned)(nb + 2);
            insert3(__uint_as_float(ka), k0, k1, k2);
            unsigned kb = (__float_as_uint(d.y) & 0xFFFFF800u) | (unsigned)(nb + 3);
            insert3(__uint_as_float(kb), k0, k1, k2);
        }
    }

    // merge the two halves: upper threads publish, lower threads insert
    if (t >= 256) {
        s_pair[(t - 256) * 3 + 0] = k0;
        s_pair[(t - 256) * 3 + 1] = k1;
        s_pair[(t - 256) * 3 + 2] = k2;
    }
    __syncthreads();
    if (t < 256) {
        insert3(s_pair[t * 3 + 0], k0, k1, k2);
        insert3(s_pair[t * 3 + 1], k0, k1, k2);
        insert3(s_pair[t * 3 + 2], k0, k1, k2);
        // epilogue: recover indices, recompute EXACT distances, interp weights
        int i0 = __float_as_uint(k0) & 0x7FF;
        int i1 = __float_as_uint(k1) & 0x7FF;
        int i2 = __float_as_uint(k2) & 0x7FF;
        float dt0 = gt - s_th[i0], dl0 = gl - s_az[i0];
        float dt1 = gt - s_th[i1], dl1 = gl - s_az[i1];
        float dt2 = gt - s_th[i2], dl2 = gl - s_az[i2];
        float d0 = fmaf(dt0, dt0, dl0 * dl0);
        float d1 = fmaf(dt1, dt1, dl1 * dl1);
        float d2 = fmaf(dt2, dt2, dl2 * dl2);
        float s = d0 + d1 + d2;
        row[j] = (d0 * s_r[i0] + d1 * s_r[i1] + d2 * s_r[i2]) / s;
    }
    __syncthreads();

    // DFT of the row: 50 modes x 8 partial sums of 32 (threads 0..399)
    if (t < 400) {
        int mm = t >> 3, q = t & 7;
        int bs = q * 32;
        float acc = 0.0f;
        int p = (bs * mm) & (NLON - 1);
        for (int i = 0; i < 32; ++i) {
            acc += row[bs + i] * ctab[p];
            p = (p + mm) & (NLON - 1);
        }
        part[t] = acc;
    }
    __syncthreads();
    if (t < MMAX) {
        const float* pp = part + t * 8;
        float v = (((pp[0] + pp[1]) + (pp[2] + pp[3])) + ((pp[4] + pp[5]) + (pp[6] + pp[7]))) *
                  (float)(2.0 * PI_D / (double)NLON);
        fre[(f * NLAT + lat) * MMAX + t] = v;
    }
}

// ---------------------------------------------------------------------------
// Kernel 2: Legendre contraction + loss. Block per (b,l), thread = mm.
// pctwT layout [l][k][m] -> lane-consecutive (coalesced) loads.
// ---------------------------------------------------------------------------
__global__ __launch_bounds__(64) void contract_loss(const float* __restrict__ fre,
                                                    const float* __restrict__ pctwT,
                                                    float* __restrict__ out) {
    int b = blockIdx.x / LMAX;   // 0..1
    int l = blockIdx.x % LMAX;   // 0..49
    int mm = threadIdx.x;        // 0..63 (50 active)
    float contrib = 0.0f;
    if (mm < MMAX) {
        const float* pw = pctwT + (size_t)l * NLAT * MMAX + mm;  // stride MMAX over k
        const float* fp = fre + (size_t)b * NLAT * MMAX + mm;
        const float* ft = fre + (size_t)(2 + b) * NLAT * MMAX + mm;
        float pc = 0.0f, tc = 0.0f;
#pragma unroll 8
        for (int k = 0; k < NLAT; ++k) {
            float w = pw[k * MMAX];
            pc += fp[k * MMAX] * w;
            tc += ft[k * MMAX] * w;
        }
        float diff = pc - tc;
        double dl_ = (double)(49 - l);
        float rw = (float)exp(-(dl_ * dl_) / 5000.0);
        contrib = diff * diff * rw * 0.5f;  // 0.5 = mean over batch of 2
    }
    for (int off = 32; off > 0; off >>= 1) contrib += __shfl_down(contrib, off);
    if (threadIdx.x == 0) atomicAdd(out, contrib);
}

// ---------------------------------------------------------------------------
extern "C" void kernel_launch(void* const* d_in, const int* in_sizes, int n_in,
                              void* d_out, int out_size, void* d_ws, size_t ws_size,
                              hipStream_t stream) {
    const float* pred = (const float*)d_in[0];
    const float* tgt = (const float*)d_in[1];
    float* ws = (float*)d_ws;

    // ws layout (floats):
    float* pctwT = ws;            // 50*128*50 = 320000
    float* fre   = ws + 320000;   // 4*128*50  =  25600
    float* out = (float*)d_out;

    fused_main<<<562, 512, 0, stream>>>(pred, tgt, pctwT, fre, out);
    contract_loss<<<2 * LMAX, 64, 0, stream>>>(fre, pctwT, out);
}

// Round 5
// 92.432 us; speedup vs baseline: 1.4435x; 1.4435x over previous
//
#include <hip/hip_runtime.h>
#include <math.h>

#define PI_D 3.14159265358979323846
#define PIF  3.14159265358979323846f
#define NLAT 128
#define NLON 256
#define LMAX 50
#define MMAX 50
#define NPTS 2048
#define NBT 16
#define NBA 32
#define NBIN (NBT * NBA)
#define WBIN 0.19634954084936207f   /* pi/16 */
#define INVW 5.092958178940651f     /* 16/pi */
#define BIG 1e30f

__device__ __forceinline__ void insert3(float d, float& k0, float& k1, float& k2) {
    float n1 = __builtin_amdgcn_fmed3f(d, k0, k1);
    float n2 = __builtin_amdgcn_fmed3f(d, k1, k2);
    k0 = fminf(d, k0);
    k1 = n1;
    k2 = n2;
}

// ---------------------------------------------------------------------------
// Kernel 1 (fused): blocks 0..511  = binned knn + interp + DFT (one field,lat)
//                   blocks 512..639 = PCTW column k = bid-512 (lane = m ->
//                   contiguous 200B stores, no cross-block line sharing).
//                   Block 512 zeroes out[0] for kernel 2's atomics.
// ---------------------------------------------------------------------------
__global__ __launch_bounds__(256) void fused_main(
    const float* __restrict__ pred, const float* __restrict__ tgt,
    float* __restrict__ pctwT, float* __restrict__ fre, float* __restrict__ out) {

    __shared__ float2 s_btl[NPTS];     // (theta, az) in bin order   16 KB
    __shared__ float  s_br[NPTS];      // radius in bin order         8 KB
    __shared__ int    s_cnt[NBIN];     // counts, then scatter cursor 2 KB
    __shared__ int    s_off[NBIN + 1]; // bin start offsets           2 KB
    __shared__ float  ctab[NLON];
    __shared__ float  row[NLON];
    __shared__ float  part[200];

    int bid = blockIdx.x;
    int t = threadIdx.x;

    if (bid >= 512) {
        // ---------------- PCTW role: one k-column, lane = m ----------------
        int k = bid - 512;                       // 0..127
        if (k == 0 && t == 0) out[0] = 0.0f;     // init for contract's atomics
        if (t < MMAX) {
            int m = t;
            double theta = PI_D * (double)k / 127.0;
            double cost = cos(theta);
            double sint = sqrt(fmax(1.0 - cost * cost, 0.0));
            // Clenshaw-Curtis weight via Chebyshev recurrence (Nn=127, odd)
            double c2 = cos(2.0 * theta);
            double two_c2 = 2.0 * c2;
            double cp = 1.0, cc = c2, v = 0.0;
            for (int tt = 1; tt <= 63; ++tt) {
                v += 2.0 * cc / (double)(4 * tt * tt - 1);
                double cn = two_c2 * cc - cp;
                cp = cc;
                cc = cn;
            }
            double w = (2.0 / 127.0) * (1.0 - v);
            if (k == 0 || k == 127) w *= 0.5;

            double pmm = sqrt(1.0 / (4.0 * PI_D));
            for (int i = 1; i <= m; ++i)
                pmm = -pmm * sqrt((2.0 * (double)i + 1.0) / (2.0 * (double)i)) * sint;

            // pctwT[(l*NLAT + k)*MMAX + m]
            float* o = pctwT + (size_t)k * MMAX + m;
            for (int l = 0; l < m; ++l) o[(size_t)l * NLAT * MMAX] = 0.0f;
            o[(size_t)m * NLAT * MMAX] = (float)(pmm * w);
            double plm2 = pmm, plm1 = 0.0;
            if (m + 1 < LMAX) {
                plm1 = sqrt(2.0 * (double)m + 3.0) * cost * pmm;
                o[(size_t)(m + 1) * NLAT * MMAX] = (float)(plm1 * w);
            }
            for (int l = m + 2; l < LMAX; ++l) {
                double ll = (double)l;
                double denom = ll * ll - (double)(m * m);
                double a = sqrt((4.0 * ll * ll - 1.0) / denom);
                double b = sqrt(((2.0 * ll + 1.0) * (double)(l - 1 + m) * (double)(l - 1 - m)) /
                                ((2.0 * ll - 3.0) * denom));
                double p = a * cost * plm1 - b * plm2;
                o[(size_t)l * NLAT * MMAX] = (float)(p * w);
                plm2 = plm1;
                plm1 = p;
            }
        }
        return;
    }

    // ---------------- KNN role ----------------
    int f = bid >> 7;
    int lat = bid & 127;
    const float* src = ((f < 2) ? pred : tgt) + (size_t)(f & 1) * NPTS * 3;

    s_cnt[t] = 0;
    s_cnt[t + 256] = 0;
    ctab[t] = (float)cos(2.0 * PI_D * (double)t / (double)NLON);
    __syncthreads();

    // to_spherical into registers (exact reference fp order) + bin counts
    float pth[8], paz[8], pr[8];
    int pbin[8];
#pragma unroll
    for (int i = 0; i < 8; ++i) {
        int n = t + 256 * i;
        float x = src[3 * n], y = src[3 * n + 1], z = src[3 * n + 2];
        float s1 = z * z;
        float s2 = s1 + y * y;
        float s3 = s2 + x * x;
        float r = sqrtf(s3);
        float rho = sqrtf(s2);
        float th = acosf(x / r);
        float a = acosf(y / rho);
        float az = (z < 0.0f) ? (a + (2.0f * PIF - 2.0f * a)) : a;
        az -= PIF;
        int bt = min(max((int)(th * INVW), 0), NBT - 1);
        int ba = min(max((int)((az + PIF) * INVW), 0), NBA - 1);
        int b = bt * NBA + ba;
        pth[i] = th; paz[i] = az; pr[i] = r; pbin[i] = b;
        atomicAdd(&s_cnt[b], 1);
    }
    __syncthreads();

    // exclusive scan of 512 counts by one wave (8 bins per lane)
    if (t == 0) s_off[NBIN] = NPTS;
    if (t < 64) {
        int base = t * 8;
        int loc[8];
        int run = 0;
#pragma unroll
        for (int i = 0; i < 8; ++i) { loc[i] = run; run += s_cnt[base + i]; }
        int x = run;
#pragma unroll
        for (int d = 1; d < 64; d <<= 1) {
            int y = __shfl_up(x, d);
            if (t >= d) x += y;
        }
        int ex = x - run;
#pragma unroll
        for (int i = 0; i < 8; ++i) s_off[base + i] = ex + loc[i];
    }
    __syncthreads();
    s_cnt[t] = s_off[t];
    s_cnt[t + 256] = s_off[t + 256];
    __syncthreads();
    // scatter into bin order
#pragma unroll
    for (int i = 0; i < 8; ++i) {
        int pos = atomicAdd(&s_cnt[pbin[i]], 1);
        s_btl[pos] = make_float2(pth[i], paz[i]);
        s_br[pos] = pr[i];
    }
    __syncthreads();

    // ---- expanding-ring 3-NN query: one grid point per thread ----
    int j = t;
    float gt = (float)((double)lat * PI_D / 128.0);
    float gl = (float)(((double)j - 128.0) * PI_D / 128.0);
    float glp = gl + PIF;
    int bt0 = lat >> 3;
    int ba0 = j >> 3;

    float k0 = BIG, k1 = BIG, k2 = BIG;
    bool done = false;
    int Rfin = 31;
    for (int R = 0; R <= 31; ++R) {
        if (__all(done)) break;
        if (!done) {
            int btl = bt0 - R, bth = bt0 + R;
            int lo = max(btl, 0), hi = min(bth, NBT - 1);
            int bal = max(ba0 - R, 0), bah = min(ba0 + R, NBA - 1);
            for (int bt = lo; bt <= hi; ++bt) {
                if (bt == btl || bt == bth) {
                    // full edge row: bins contiguous in memory
                    int i0 = s_off[bt * NBA + bal];
                    int i1 = s_off[bt * NBA + bah + 1];
                    for (int i = i0; i < i1; ++i) {
                        float2 tl = s_btl[i];
                        float dt = gt - tl.x, dl = gl - tl.y;
                        float d = fmaf(dt, dt, dl * dl);
                        insert3(d, k0, k1, k2);
                    }
                } else {
                    if (ba0 - R >= 0) {
                        int b = bt * NBA + ba0 - R;
                        for (int i = s_off[b]; i < s_off[b + 1]; ++i) {
                            float2 tl = s_btl[i];
                            float dt = gt - tl.x, dl = gl - tl.y;
                            float d = fmaf(dt, dt, dl * dl);
                            insert3(d, k0, k1, k2);
                        }
                    }
                    if (ba0 + R <= NBA - 1) {
                        int b = bt * NBA + ba0 + R;
                        for (int i = s_off[b]; i < s_off[b + 1]; ++i) {
                            float2 tl = s_btl[i];
                            float dt = gt - tl.x, dl = gl - tl.y;
                            float d = fmaf(dt, dt, dl * dl);
                            insert3(d, k0, k1, k2);
                        }
                    }
                }
            }
            // safe radius = distance to nearest unscanned region boundary
            float safe = BIG;
            if (bt0 - R > 0)       safe = fminf(safe, gt - (float)(bt0 - R) * WBIN);
            if (bt0 + R < NBT - 1) safe = fminf(safe, (float)(bt0 + R + 1) * WBIN - gt);
            if (ba0 - R > 0)       safe = fminf(safe, glp - (float)(ba0 - R) * WBIN);
            if (ba0 + R < NBA - 1) safe = fminf(safe, (float)(ba0 + R + 1) * WBIN - glp);
            if (k2 <= safe * safe) { done = true; Rfin = R; }
        }
    }

    // pass 2: recover radii of the 3 winners by exact distance match
    float r0 = 0.0f, r1 = 0.0f, r2 = 0.0f;
    bool f0 = false, f1 = false, f2 = false;
    {
        int lo = max(bt0 - Rfin, 0), hi = min(bt0 + Rfin, NBT - 1);
        int bal = max(ba0 - Rfin, 0), bah = min(ba0 + Rfin, NBA - 1);
        for (int bt = lo; bt <= hi; ++bt) {
            int i0 = s_off[bt * NBA + bal];
            int i1 = s_off[bt * NBA + bah + 1];
            for (int i = i0; i < i1; ++i) {
                float2 tl = s_btl[i];
                float dt = gt - tl.x, dl = gl - tl.y;
                float d = fmaf(dt, dt, dl * dl);
                if (d == k0 && !f0)      { r0 = s_br[i]; f0 = true; }
                else if (d == k1 && !f1) { r1 = s_br[i]; f1 = true; }
                else if (d == k2 && !f2) { r2 = s_br[i]; f2 = true; }
            }
        }
    }
    float s = k0 + k1 + k2;
    row[j] = (k0 * r0 + k1 * r1 + k2 * r2) / s;
    __syncthreads();

    // DFT of the row: 50 modes x 4 partial sums of 64 (threads 0..199)
    if (t < 200) {
        int mm = t >> 2, q = t & 3;
        int bs = q * 64;
        float acc = 0.0f;
        int p = (bs * mm) & (NLON - 1);
        for (int i = 0; i < 64; ++i) {
            acc += row[bs + i] * ctab[p];
            p = (p + mm) & (NLON - 1);
        }
        part[t] = acc;
    }
    __syncthreads();
    if (t < MMAX) {
        const float* pp = part + t * 4;
        fre[(f * NLAT + lat) * MMAX + t] =
            ((pp[0] + pp[1]) + (pp[2] + pp[3])) * (float)(2.0 * PI_D / (double)NLON);
    }
}

// ---------------------------------------------------------------------------
// Kernel 2: Legendre contraction + loss. Block per (b,l); 256 threads =
// (mm 0..63) x (k-quarter 0..3); LDS reduce; one atomic per block.
// ---------------------------------------------------------------------------
__global__ __launch_bounds__(256) void contract_loss(const float* __restrict__ fre,
                                                     const float* __restrict__ pctwT,
                                                     float* __restrict__ out) {
    int b = blockIdx.x / LMAX;
    int l = blockIdx.x % LMAX;
    int mm = threadIdx.x & 63;
    int kq = threadIdx.x >> 6;
    __shared__ float sp[4][64], st_[4][64];
    float pc = 0.0f, tc = 0.0f;
    if (mm < MMAX) {
        const float* pw = pctwT + ((size_t)l * NLAT + kq * 32) * MMAX + mm;
        const float* fp = fre + ((size_t)b * NLAT + kq * 32) * MMAX + mm;
        const float* ft = fre + ((size_t)(2 + b) * NLAT + kq * 32) * MMAX + mm;
#pragma unroll 8
        for (int k = 0; k < 32; ++k) {
            float w = pw[k * MMAX];
            pc += fp[k * MMAX] * w;
            tc += ft[k * MMAX] * w;
        }
    }
    sp[kq][mm] = pc;
    st_[kq][mm] = tc;
    __syncthreads();
    if (threadIdx.x < 64) {
        int m2 = threadIdx.x;
        float pcs = (sp[0][m2] + sp[1][m2]) + (sp[2][m2] + sp[3][m2]);
        float tcs = (st_[0][m2] + st_[1][m2]) + (st_[2][m2] + st_[3][m2]);
        float diff = pcs - tcs;
        double dl_ = (double)(49 - l);
        float rw = (float)exp(-(dl_ * dl_) / 5000.0);
        float contrib = (m2 < MMAX) ? diff * diff * rw * 0.5f : 0.0f;
        for (int off = 32; off > 0; off >>= 1) contrib += __shfl_down(contrib, off);
        if (m2 == 0) atomicAdd(out, contrib);
    }
}

// ---------------------------------------------------------------------------
extern "C" void kernel_launch(void* const* d_in, const int* in_sizes, int n_in,
                              void* d_out, int out_size, void* d_ws, size_t ws_size,
                              hipStream_t stream) {
    const float* pred = (const float*)d_in[0];
    const float* tgt = (const float*)d_in[1];
    float* ws = (float*)d_ws;

    float* pctwT = ws;            // 50*128*50 = 320000 floats
    float* fre   = ws + 320000;   // 4*128*50  =  25600 floats
    float* out = (float*)d_out;

    fused_main<<<640, 256, 0, stream>>>(pred, tgt, pctwT, fre, out);
    contract_loss<<<2 * LMAX, 256, 0, stream>>>(fre, pctwT, out);
}

// Round 6
// 86.300 us; speedup vs baseline: 1.5461x; 1.0711x over previous
//
#include <hip/hip_runtime.h>
#include <math.h>

#define PI_D 3.14159265358979323846
#define PIF  3.14159265358979323846f
#define NLAT 128
#define NLON 256
#define LMAX 50
#define MMAX 50
#define NPTS 2048
#define NBT 16
#define NBA 32
#define NBIN (NBT * NBA)
#define WBIN 0.19634954084936207f   /* pi/16 */
#define INVW 5.092958178940651f     /* 16/pi */
#define BIG 1e30f
#define KMASK 0xFFFFF800u           /* high 21 bits of distance, low 11 = index */

__device__ __forceinline__ void insert3(float kf, float& k0, float& k1, float& k2) {
    float n1 = __builtin_amdgcn_fmed3f(kf, k0, k1);
    float n2 = __builtin_amdgcn_fmed3f(kf, k1, k2);
    k0 = fminf(kf, k0);
    k1 = n1;
    k2 = n2;
}

__device__ __forceinline__ float mkkey(float gt, float gl, float2 tl, int idx) {
    float dt = gt - tl.x, dl = gl - tl.y;
    float d = fmaf(dt, dt, dl * dl);
    return __uint_as_float((__float_as_uint(d) & KMASK) | (unsigned)idx);
}

// ---------------------------------------------------------------------------
// Kernel 1 (fused): blocks 0..511  = binned knn + interp + DFT (one field,lat)
//                   blocks 512..639 = PCTW column k = bid-512 (lane = m).
//                   Block 512 zeroes out[0] for kernel 2's atomics.
// ---------------------------------------------------------------------------
__global__ __launch_bounds__(256) void fused_main(
    const float* __restrict__ pred, const float* __restrict__ tgt,
    float* __restrict__ pctwT, float* __restrict__ fre, float* __restrict__ out) {

    __shared__ float2 s_btl[NPTS];     // (theta, az) in bin order   16 KB
    __shared__ float  s_br[NPTS];      // radius in bin order         8 KB
    __shared__ int    s_cnt[NBIN];     // counts, then scatter cursor 2 KB
    __shared__ int    s_off[NBIN + 1]; // bin start offsets           2 KB
    __shared__ float  ctab[NLON];
    __shared__ float  row[NLON];
    __shared__ float  part[200];

    int bid = blockIdx.x;
    int t = threadIdx.x;

    if (bid >= 512) {
        // ---------------- PCTW role: one k-column, lane = m ----------------
        int k = bid - 512;                       // 0..127
        if (k == 0 && t == 0) out[0] = 0.0f;     // init for contract's atomics
        if (t < MMAX) {
            int m = t;
            double theta = PI_D * (double)k / 127.0;
            double cost = cos(theta);
            double sint = sqrt(fmax(1.0 - cost * cost, 0.0));
            // Clenshaw-Curtis weight via Chebyshev recurrence (Nn=127, odd)
            double c2 = cos(2.0 * theta);
            double two_c2 = 2.0 * c2;
            double cp = 1.0, cc = c2, v = 0.0;
            for (int tt = 1; tt <= 63; ++tt) {
                v += 2.0 * cc / (double)(4 * tt * tt - 1);
                double cn = two_c2 * cc - cp;
                cp = cc;
                cc = cn;
            }
            double w = (2.0 / 127.0) * (1.0 - v);
            if (k == 0 || k == 127) w *= 0.5;

            double pmm = sqrt(1.0 / (4.0 * PI_D));
            for (int i = 1; i <= m; ++i)
                pmm = -pmm * sqrt((2.0 * (double)i + 1.0) / (2.0 * (double)i)) * sint;

            float* o = pctwT + (size_t)k * MMAX + m;  // pctwT[(l*NLAT+k)*MMAX+m]
            for (int l = 0; l < m; ++l) o[(size_t)l * NLAT * MMAX] = 0.0f;
            o[(size_t)m * NLAT * MMAX] = (float)(pmm * w);
            double plm2 = pmm, plm1 = 0.0;
            if (m + 1 < LMAX) {
                plm1 = sqrt(2.0 * (double)m + 3.0) * cost * pmm;
                o[(size_t)(m + 1) * NLAT * MMAX] = (float)(plm1 * w);
            }
            for (int l = m + 2; l < LMAX; ++l) {
                double ll = (double)l;
                double denom = ll * ll - (double)(m * m);
                double a = sqrt((4.0 * ll * ll - 1.0) / denom);
                double b = sqrt(((2.0 * ll + 1.0) * (double)(l - 1 + m) * (double)(l - 1 - m)) /
                                ((2.0 * ll - 3.0) * denom));
                double p = a * cost * plm1 - b * plm2;
                o[(size_t)l * NLAT * MMAX] = (float)(p * w);
                plm2 = plm1;
                plm1 = p;
            }
        }
        return;
    }

    // ---------------- KNN role ----------------
    int f = bid >> 7;
    int lat = bid & 127;
    const float* src = ((f < 2) ? pred : tgt) + (size_t)(f & 1) * NPTS * 3;

    s_cnt[t] = 0;
    s_cnt[t + 256] = 0;
    ctab[t] = (float)cos(2.0 * PI_D * (double)t / (double)NLON);
    __syncthreads();

    // to_spherical into registers (exact reference fp order) + bin counts
    float pth[8], paz[8], pr[8];
    int pbin[8];
#pragma unroll
    for (int i = 0; i < 8; ++i) {
        int n = t + 256 * i;
        float x = src[3 * n], y = src[3 * n + 1], z = src[3 * n + 2];
        float s1 = z * z;
        float s2 = s1 + y * y;
        float s3 = s2 + x * x;
        float r = sqrtf(s3);
        float rho = sqrtf(s2);
        float th = acosf(x / r);
        float a = acosf(y / rho);
        float az = (z < 0.0f) ? (a + (2.0f * PIF - 2.0f * a)) : a;
        az -= PIF;
        int bt = min(max((int)(th * INVW), 0), NBT - 1);
        int ba = min(max((int)((az + PIF) * INVW), 0), NBA - 1);
        int b = bt * NBA + ba;
        pth[i] = th; paz[i] = az; pr[i] = r; pbin[i] = b;
        atomicAdd(&s_cnt[b], 1);
    }
    __syncthreads();

    // exclusive scan of 512 counts by one wave (8 bins per lane)
    if (t == 0) s_off[NBIN] = NPTS;
    if (t < 64) {
        int base = t * 8;
        int loc[8];
        int run = 0;
#pragma unroll
        for (int i = 0; i < 8; ++i) { loc[i] = run; run += s_cnt[base + i]; }
        int x = run;
#pragma unroll
        for (int d = 1; d < 64; d <<= 1) {
            int y = __shfl_up(x, d);
            if (t >= d) x += y;
        }
        int ex = x - run;
#pragma unroll
        for (int i = 0; i < 8; ++i) s_off[base + i] = ex + loc[i];
    }
    __syncthreads();
    s_cnt[t] = s_off[t];
    s_cnt[t + 256] = s_off[t + 256];
    __syncthreads();
#pragma unroll
    for (int i = 0; i < 8; ++i) {
        int pos = atomicAdd(&s_cnt[pbin[i]], 1);
        s_btl[pos] = make_float2(pth[i], paz[i]);
        s_br[pos] = pr[i];
    }
    __syncthreads();

    // ---- 3-NN query: one grid point per thread, packed keys ----
    int j = t;
    float gt = (float)((double)lat * PI_D / 128.0);
    float gl = (float)(((double)j - 128.0) * PI_D / 128.0);
    float glp = gl + PIF;
    int bt0 = lat >> 3;     // block-uniform
    int ba0 = j >> 3;

    float k0 = BIG, k1 = BIG, k2 = BIG;

    // initial 3x3-bin pass: <=3 uniform row iterations, contiguous segments,
    // unrolled x4 so LDS loads pipeline.
    {
        int rtl = max(bt0 - 1, 0), rth = min(bt0 + 1, NBT - 1);
        int bal = max(ba0 - 1, 0), bah = min(ba0 + 1, NBA - 1);
        for (int bt = rtl; bt <= rth; ++bt) {
            int i = s_off[bt * NBA + bal];
            int i1 = s_off[bt * NBA + bah + 1];
            for (; i + 4 <= i1; i += 4) {
                float2 a0 = s_btl[i];
                float2 a1 = s_btl[i + 1];
                float2 a2 = s_btl[i + 2];
                float2 a3 = s_btl[i + 3];
                insert3(mkkey(gt, gl, a0, i), k0, k1, k2);
                insert3(mkkey(gt, gl, a1, i + 1), k0, k1, k2);
                insert3(mkkey(gt, gl, a2, i + 2), k0, k1, k2);
                insert3(mkkey(gt, gl, a3, i + 3), k0, k1, k2);
            }
            for (; i < i1; ++i)
                insert3(mkkey(gt, gl, s_btl[i], i), k0, k1, k2);
        }
    }

    // safe-radius check after R=1 (truncated k2 <= true k2, conservative
    // within 2^-11 relative -- fine vs threshold)
    bool done;
    {
        float safe = BIG;
        if (bt0 - 1 > 0)       safe = fminf(safe, gt - (float)(bt0 - 1) * WBIN);
        if (bt0 + 1 < NBT - 1) safe = fminf(safe, (float)(bt0 + 2) * WBIN - gt);
        if (ba0 - 1 > 0)       safe = fminf(safe, glp - (float)(ba0 - 1) * WBIN);
        if (ba0 + 1 < NBA - 1) safe = fminf(safe, (float)(ba0 + 2) * WBIN - glp);
        done = (k2 <= safe * safe);
    }

    // fallback expanding rings R>=2 (rare: polar rows / sparse patches)
    for (int R = 2; R <= 31; ++R) {
        if (__all(done)) break;
        if (!done) {
            int btl = bt0 - R, bth = bt0 + R;
            int lo = max(btl, 0), hi = min(bth, NBT - 1);
            int bal = max(ba0 - R, 0), bah = min(ba0 + R, NBA - 1);
            for (int bt = lo; bt <= hi; ++bt) {
                if (bt == btl || bt == bth) {
                    int i0 = s_off[bt * NBA + bal];
                    int i1 = s_off[bt * NBA + bah + 1];
                    for (int i = i0; i < i1; ++i)
                        insert3(mkkey(gt, gl, s_btl[i], i), k0, k1, k2);
                } else {
                    if (ba0 - R >= 0) {
                        int b = bt * NBA + ba0 - R;
                        for (int i = s_off[b]; i < s_off[b + 1]; ++i)
                            insert3(mkkey(gt, gl, s_btl[i], i), k0, k1, k2);
                    }
                    if (ba0 + R <= NBA - 1) {
                        int b = bt * NBA + ba0 + R;
                        for (int i = s_off[b]; i < s_off[b + 1]; ++i)
                            insert3(mkkey(gt, gl, s_btl[i], i), k0, k1, k2);
                    }
                }
            }
            float safe = BIG;
            if (bt0 - R > 0)       safe = fminf(safe, gt - (float)(bt0 - R) * WBIN);
            if (bt0 + R < NBT - 1) safe = fminf(safe, (float)(bt0 + R + 1) * WBIN - gt);
            if (ba0 - R > 0)       safe = fminf(safe, glp - (float)(ba0 - R) * WBIN);
            if (ba0 + R < NBA - 1) safe = fminf(safe, (float)(ba0 + R + 1) * WBIN - glp);
            if (k2 <= safe * safe) done = true;
        }
    }

    // epilogue: indices from keys, exact distances, interp weights
    {
        int i0 = __float_as_uint(k0) & 0x7FF;
        int i1 = __float_as_uint(k1) & 0x7FF;
        int i2 = __float_as_uint(k2) & 0x7FF;
        float2 p0 = s_btl[i0];
        float2 p1 = s_btl[i1];
        float2 p2 = s_btl[i2];
        float dt0 = gt - p0.x, dl0 = gl - p0.y;
        float dt1 = gt - p1.x, dl1 = gl - p1.y;
        float dt2 = gt - p2.x, dl2 = gl - p2.y;
        float d0 = fmaf(dt0, dt0, dl0 * dl0);
        float d1 = fmaf(dt1, dt1, dl1 * dl1);
        float d2 = fmaf(dt2, dt2, dl2 * dl2);
        float s = d0 + d1 + d2;
        row[j] = (d0 * s_br[i0] + d1 * s_br[i1] + d2 * s_br[i2]) / s;
    }
    __syncthreads();

    // DFT of the row: 50 modes x 4 partial sums of 64 (threads 0..199)
    if (t < 200) {
        int mm = t >> 2, q = t & 3;
        int bs = q * 64;
        float acc = 0.0f;
        int p = (bs * mm) & (NLON - 1);
        for (int i = 0; i < 64; ++i) {
            acc += row[bs + i] * ctab[p];
            p = (p + mm) & (NLON - 1);
        }
        part[t] = acc;
    }
    __syncthreads();
    if (t < MMAX) {
        const float* pp = part + t * 4;
        fre[(f * NLAT + lat) * MMAX + t] =
            ((pp[0] + pp[1]) + (pp[2] + pp[3])) * (float)(2.0 * PI_D / (double)NLON);
    }
}

// ---------------------------------------------------------------------------
// Kernel 2: Legendre contraction + loss. Block per (b,l); 256 threads =
// (mm 0..63) x (k-quarter 0..3); LDS reduce; one atomic per block.
// ---------------------------------------------------------------------------
__global__ __launch_bounds__(256) void contract_loss(const float* __restrict__ fre,
                                                     const float* __restrict__ pctwT,
                                                     float* __restrict__ out) {
    int b = blockIdx.x / LMAX;
    int l = blockIdx.x % LMAX;
    int mm = threadIdx.x & 63;
    int kq = threadIdx.x >> 6;
    __shared__ float sp[4][64], st_[4][64];
    float pc = 0.0f, tc = 0.0f;
    if (mm < MMAX) {
        const float* pw = pctwT + ((size_t)l * NLAT + kq * 32) * MMAX + mm;
        const float* fp = fre + ((size_t)b * NLAT + kq * 32) * MMAX + mm;
        const float* ft = fre + ((size_t)(2 + b) * NLAT + kq * 32) * MMAX + mm;
#pragma unroll 8
        for (int k = 0; k < 32; ++k) {
            float w = pw[k * MMAX];
            pc += fp[k * MMAX] * w;
            tc += ft[k * MMAX] * w;
        }
    }
    sp[kq][mm] = pc;
    st_[kq][mm] = tc;
    __syncthreads();
    if (threadIdx.x < 64) {
        int m2 = threadIdx.x;
        float pcs = (sp[0][m2] + sp[1][m2]) + (sp[2][m2] + sp[3][m2]);
        float tcs = (st_[0][m2] + st_[1][m2]) + (st_[2][m2] + st_[3][m2]);
        float diff = pcs - tcs;
        double dl_ = (double)(49 - l);
        float rw = (float)exp(-(dl_ * dl_) / 5000.0);
        float contrib = (m2 < MMAX) ? diff * diff * rw * 0.5f : 0.0f;
        for (int off = 32; off > 0; off >>= 1) contrib += __shfl_down(contrib, off);
        if (m2 == 0) atomicAdd(out, contrib);
    }
}

// ---------------------------------------------------------------------------
extern "C" void kernel_launch(void* const* d_in, const int* in_sizes, int n_in,
                              void* d_out, int out_size, void* d_ws, size_t ws_size,
                              hipStream_t stream) {
    const float* pred = (const float*)d_in[0];
    const float* tgt = (const float*)d_in[1];
    float* ws = (float*)d_ws;

    float* pctwT = ws;            // 50*128*50 = 320000 floats
    float* fre   = ws + 320000;   // 4*128*50  =  25600 floats
    float* out = (float*)d_out;

    fused_main<<<640, 256, 0, stream>>>(pred, tgt, pctwT, fre, out);
    contract_loss<<<2 * LMAX, 256, 0, stream>>>(fre, pctwT, out);
}